// Round 1
// baseline (103.900 us; speedup 1.0000x reference)
//
#include <hip/hip_runtime.h>
#include <hip/hip_bf16.h>
#include <stdint.h>

typedef __attribute__((ext_vector_type(4))) float fx4;
typedef __attribute__((ext_vector_type(8))) short bx8;
typedef unsigned short u16;

#define DIM 64
#define MAT (DIM*DIM)

// ws layout:
//   float  T_rm[2][4096]   @ float off 0      (T = prims^T, row-major)
//   float  T_cm[2][4096]   @ float off 8192   (T col-major)
//   u16    rm_bf16[64][4096] @ byte off 65536          (table, row-major bf16)
//   u16    cm_bf16[64][4096] @ byte off 65536+524288   (table, col-major bf16)

__device__ __forceinline__ u16 f2bf(float x) {
    unsigned u = __float_as_uint(x);
    unsigned r = (u + 0x7FFFu + ((u >> 16) & 1u)) >> 16;
    return (u16)r;
}

// C = X @ Y  (64x64 fp32, LDS). X given col-major: Xcm[k*64+r] = X[r][k]. Y row-major.
// Writes Ccm (col-major) and/or Crm (row-major), scaled by outSign.
// Optional epilogue: += qa*I + qb*M (M row-major).
// 128 threads: tile 4 rows x 8 cols per thread.
__device__ __forceinline__ void mm64(int tid,
        const float* __restrict__ Xcm, const float* __restrict__ Yrm,
        float* __restrict__ Ccm, float* __restrict__ Crm,
        float outSign, bool addQ, float qa, float qb, const float* __restrict__ Mrm)
{
    const int tx = tid & 7, ty = tid >> 3;
    const int c0 = tx * 8, r0 = ty * 4;
    float acc[4][8];
#pragma unroll
    for (int i = 0; i < 4; ++i)
#pragma unroll
        for (int j = 0; j < 8; ++j) acc[i][j] = 0.f;

#pragma unroll 4
    for (int k = 0; k < 64; ++k) {
        fx4 xv = *(const fx4*)(Xcm + k * 64 + r0);
        fx4 y0 = *(const fx4*)(Yrm + k * 64 + c0);
        fx4 y1 = *(const fx4*)(Yrm + k * 64 + c0 + 4);
#pragma unroll
        for (int i = 0; i < 4; ++i) {
#pragma unroll
            for (int j = 0; j < 4; ++j) {
                acc[i][j]     += xv[i] * y0[j];
                acc[i][j + 4] += xv[i] * y1[j];
            }
        }
    }

    float res[4][8];
    if (addQ) {
#pragma unroll
        for (int i = 0; i < 4; ++i) {
            fx4 m0 = *(const fx4*)(Mrm + (r0 + i) * 64 + c0);
            fx4 m1 = *(const fx4*)(Mrm + (r0 + i) * 64 + c0 + 4);
#pragma unroll
            for (int j = 0; j < 4; ++j) {
                res[i][j]     = outSign * acc[i][j]     + qb * m0[j] + ((r0 + i) == (c0 + j)     ? qa : 0.f);
                res[i][j + 4] = outSign * acc[i][j + 4] + qb * m1[j] + ((r0 + i) == (c0 + j + 4) ? qa : 0.f);
            }
        }
    } else {
#pragma unroll
        for (int i = 0; i < 4; ++i)
#pragma unroll
            for (int j = 0; j < 8; ++j) res[i][j] = outSign * acc[i][j];
    }

    if (Ccm) {
#pragma unroll
        for (int j = 0; j < 8; ++j) {
            fx4 v = { res[0][j], res[1][j], res[2][j], res[3][j] };
            *(fx4*)(Ccm + (c0 + j) * 64 + r0) = v;
        }
    }
    if (Crm) {
#pragma unroll
        for (int i = 0; i < 4; ++i) {
            fx4 a = { res[i][0], res[i][1], res[i][2], res[i][3] };
            fx4 b = { res[i][4], res[i][5], res[i][6], res[i][7] };
            *(fx4*)(Crm + (r0 + i) * 64 + c0) = a;
            *(fx4*)(Crm + (r0 + i) * 64 + c0 + 4) = b;
        }
    }
}

// K1: expm(P - P^T) per generator; writes T_rm = expm^T (rm) and T_cm.
__global__ __launch_bounds__(128) void expm_kernel(const float* __restrict__ praw,
                                                   float* __restrict__ ws)
{
    __shared__ float buf0[MAT], buf1[MAT], buf2[MAT], buf3[MAT];  // 64 KB
    const int g = blockIdx.x, tid = threadIdx.x;
    const int tx = tid & 7, ty = tid >> 3;
    const int c0 = tx * 8, r0 = ty * 4;
    const float* P = praw + g * MAT;

    // coeffs 1/n!
    const float Cf[14] = {
        1.f, 1.f, 0.5f, (float)(1.0/6), (float)(1.0/24), (float)(1.0/120),
        (float)(1.0/720), (float)(1.0/5040), (float)(1.0/40320), (float)(1.0/362880),
        (float)(1.0/3628800), (float)(1.0/39916800),
        (float)(1.0/479001600.0), (float)(1.0/6227020800.0) };

    // M = (P - P^T) / 64 -> buf0 (rm)
#pragma unroll
    for (int i = 0; i < 4; ++i) {
        int r = r0 + i;
#pragma unroll
        for (int j = 0; j < 8; ++j) {
            int c = c0 + j;
            buf0[r * 64 + c] = (P[r * 64 + c] - P[c * 64 + r]) * (1.0f / 64.0f);
        }
    }
    __syncthreads();

    // M2 = M@M -> buf1 (rm). Passing Mrm as Xcm computes M^T@M = -M@M, so outSign=-1.
    mm64(tid, buf0, buf0, nullptr, buf1, -1.f, false, 0.f, 0.f, nullptr);
    __syncthreads();

    // R = q6 = C12*I + C13*M -> buf2 (cm)
    {
        float t[4][8];
#pragma unroll
        for (int i = 0; i < 4; ++i) {
            fx4 m0 = *(const fx4*)(buf0 + (r0 + i) * 64 + c0);
            fx4 m1 = *(const fx4*)(buf0 + (r0 + i) * 64 + c0 + 4);
#pragma unroll
            for (int j = 0; j < 4; ++j) {
                t[i][j]     = Cf[13] * m0[j] + ((r0 + i) == (c0 + j)     ? Cf[12] : 0.f);
                t[i][j + 4] = Cf[13] * m1[j] + ((r0 + i) == (c0 + j + 4) ? Cf[12] : 0.f);
            }
        }
#pragma unroll
        for (int j = 0; j < 8; ++j) {
            fx4 v = { t[0][j], t[1][j], t[2][j], t[3][j] };
            *(fx4*)(buf2 + (c0 + j) * 64 + r0) = v;
        }
    }
    __syncthreads();

    // Horner: R = R@M2 + (C[2i] I + C[2i+1] M), i = 5..0
    float* ping = buf2; float* pong = buf3;
    for (int i = 5; i >= 0; --i) {
        mm64(tid, ping, buf1, pong, nullptr, 1.f, true, Cf[2 * i], Cf[2 * i + 1], buf0);
        __syncthreads();
        float* t2 = ping; ping = pong; pong = t2;
    }
    // ping == buf2 (cm of R). Transpose -> buf1 (rm of R).
    {
        float t[4][8];
#pragma unroll
        for (int j = 0; j < 8; ++j) {
            fx4 v = *(const fx4*)(buf2 + (c0 + j) * 64 + r0);
            t[0][j] = v[0]; t[1][j] = v[1]; t[2][j] = v[2]; t[3][j] = v[3];
        }
        __syncthreads();
#pragma unroll
        for (int i = 0; i < 4; ++i) {
            fx4 a = { t[i][0], t[i][1], t[i][2], t[i][3] };
            fx4 b = { t[i][4], t[i][5], t[i][6], t[i][7] };
            *(fx4*)(buf1 + (r0 + i) * 64 + c0) = a;
            *(fx4*)(buf1 + (r0 + i) * 64 + c0 + 4) = b;
        }
    }
    __syncthreads();

    // 6 squarings: S = R@R (needs cm + rm of R, produces both)
    float* cmIn = buf2; float* rmIn = buf1; float* cmOut = buf3; float* rmOut = buf0;
    for (int s = 0; s < 6; ++s) {
        mm64(tid, cmIn, rmIn, cmOut, rmOut, 1.f, false, 0.f, 0.f, nullptr);
        __syncthreads();
        float* a = cmIn; cmIn = cmOut; cmOut = a;
        float* b = rmIn; rmIn = rmOut; rmOut = b;
    }
    // final: cmIn = cm(R) = rm(T);  rmIn = rm(R) = cm(T)   (T = R^T)
    float* Trm = ws + g * MAT;
    float* Tcm = ws + 2 * MAT + g * MAT;
    for (int e = tid; e < MAT / 4; e += 128) {
        ((fx4*)Trm)[e] = ((const fx4*)cmIn)[e];
        ((fx4*)Tcm)[e] = ((const fx4*)rmIn)[e];
    }
}

// K2: table of all chain products for p in [0,64). Each block independent chain.
__global__ __launch_bounds__(128) void table_kernel(const float* __restrict__ ws,
                                                    u16* __restrict__ rm_bf,
                                                    u16* __restrict__ cm_bf)
{
    __shared__ float T0[MAT], T1[MAT], Ma[MAT], Mb[MAT];  // 64 KB
    const int p = blockIdx.x, tid = threadIdx.x;
    u16* orm = rm_bf + p * MAT;
    u16* ocm = cm_bf + p * MAT;

    if (p < 2) {  // identity
        for (int e = tid; e < MAT; e += 128) {
            u16 v = ((e / 64) == (e % 64)) ? (u16)0x3F80 : (u16)0;
            orm[e] = v; ocm[e] = v;
        }
        return;
    }

    for (int e = tid; e < MAT / 4; e += 128) {
        ((fx4*)T0)[e] = ((const fx4*)(ws))[e];
        ((fx4*)T1)[e] = ((const fx4*)(ws + MAT))[e];
    }
    // M init = cm(T[b0]) = T_cm[p&1]
    {
        const float* src = ws + 2 * MAT + (p & 1) * MAT;
        for (int e = tid; e < MAT / 4; e += 128)
            ((fx4*)Ma)[e] = ((const fx4*)src)[e];
    }
    __syncthreads();

    const int d = 31 - __clz(p);
    float* ping = Ma; float* pong = Mb;
    for (int i = 1; i < d; ++i) {
        const float* Y = ((p >> i) & 1) ? T1 : T0;
        mm64(tid, ping, Y, pong, nullptr, 1.f, false, 0.f, 0.f, nullptr);
        __syncthreads();
        float* t2 = ping; ping = pong; pong = t2;
    }

    // write bf16 rm + cm from ping (cm of M)
    const int tx = tid & 7, ty = tid >> 3;
    const int c0 = tx * 8, r0 = ty * 4;
    float t[4][8];
#pragma unroll
    for (int j = 0; j < 8; ++j) {
        fx4 v = *(const fx4*)(ping + (c0 + j) * 64 + r0);
        t[0][j] = v[0]; t[1][j] = v[1]; t[2][j] = v[2]; t[3][j] = v[3];
    }
#pragma unroll
    for (int i = 0; i < 4; ++i) {
        union { u16 u[8]; uint4 v; } pk;
#pragma unroll
        for (int j = 0; j < 8; ++j) pk.u[j] = f2bf(t[i][j]);
        *(uint4*)(orm + (r0 + i) * 64 + c0) = pk.v;
    }
#pragma unroll
    for (int j = 0; j < 8; ++j) {
        union { u16 u[4]; uint2 v; } pk;
#pragma unroll
        for (int i = 0; i < 4; ++i) pk.u[i] = f2bf(t[i][j]);
        *(uint2*)(ocm + (c0 + j) * 64 + r0) = pk.v;
    }
}

// K3: per-token output: content + maps (copy or one MFMA matmul of two table entries)
__global__ __launch_bounds__(256) void out_kernel(const int* __restrict__ tt,
                                                  const int* __restrict__ tv,
                                                  const int* __restrict__ npos,
                                                  const float* __restrict__ embed,
                                                  const u16* __restrict__ rm_bf,
                                                  const u16* __restrict__ cm_bf,
                                                  float* __restrict__ out)
{
    const int flat = blockIdx.x, tid = threadIdx.x;
    const int pos = npos[flat];

    if (tid < 64) {
        const int t = tt[flat], v = tv[flat];
        int idx; bool valid = true;
        if (t == 0)      idx = 0;
        else if (t == 1) idx = v + 1;
        else if (t == 2) idx = v + 5;
        else if (t == 4) idx = 8;
        else if (t == 3 && v == -1) idx = 10;
        else { idx = 0; valid = false; }
        out[flat * 64 + tid] = valid ? embed[idx * 64 + tid] : 0.f;
    }

    float* om = out + 4096 * 64 + (size_t)flat * MAT;

    if (pos < 64) {
        const u16* src = rm_bf + pos * MAT;
        for (int e = tid * 8; e < MAT; e += 256 * 8) {
            uint4 ld = *(const uint4*)(src + e);
            fx4 lo, hi;
            lo[0] = __uint_as_float(ld.x << 16); lo[1] = __uint_as_float(ld.x & 0xFFFF0000u);
            lo[2] = __uint_as_float(ld.y << 16); lo[3] = __uint_as_float(ld.y & 0xFFFF0000u);
            hi[0] = __uint_as_float(ld.z << 16); hi[1] = __uint_as_float(ld.z & 0xFFFF0000u);
            hi[2] = __uint_as_float(ld.w << 16); hi[3] = __uint_as_float(ld.w & 0xFFFF0000u);
            *(fx4*)(om + e) = lo;
            *(fx4*)(om + e + 4) = hi;
        }
    } else {
        const int lo5 = (pos & 31) | 32;
        const int hi5 = pos >> 5;
        const u16* Arm = rm_bf + lo5 * MAT;   // A = E_lo, row-major
        const u16* Bcm = cm_bf + hi5 * MAT;   // B = E_hi, col-major
        const int w = tid >> 6, l = tid & 63;
        const int lr = l & 15, lk = (l >> 4) * 8;

        bx8 a0 = *(const bx8*)(Arm + (w * 16 + lr) * 64 + lk);
        bx8 a1 = *(const bx8*)(Arm + (w * 16 + lr) * 64 + 32 + lk);
#pragma unroll
        for (int ct = 0; ct < 4; ++ct) {
            const u16* bp = Bcm + (ct * 16 + lr) * 64 + lk;
            bx8 b0 = *(const bx8*)(bp);
            bx8 b1 = *(const bx8*)(bp + 32);
            fx4 acc = { 0.f, 0.f, 0.f, 0.f };
            acc = __builtin_amdgcn_mfma_f32_16x16x32_bf16(a0, b0, acc, 0, 0, 0);
            acc = __builtin_amdgcn_mfma_f32_16x16x32_bf16(a1, b1, acc, 0, 0, 0);
            const int orow = w * 16 + (l >> 4) * 4;
            const int oc = ct * 16 + lr;
#pragma unroll
            for (int r = 0; r < 4; ++r)
                om[(orow + r) * 64 + oc] = acc[r];
        }
    }
}

extern "C" void kernel_launch(void* const* d_in, const int* in_sizes, int n_in,
                              void* d_out, int out_size, void* d_ws, size_t ws_size,
                              hipStream_t stream)
{
    const int*   tt    = (const int*)d_in[0];
    const int*   tv    = (const int*)d_in[1];
    const int*   np    = (const int*)d_in[2];
    const float* embed = (const float*)d_in[3];
    const float* praw  = (const float*)d_in[4];
    float* out = (float*)d_out;

    float* ws    = (float*)d_ws;
    u16*   rm_bf = (u16*)((char*)d_ws + 65536);
    u16*   cm_bf = (u16*)((char*)d_ws + 65536 + 524288);

    expm_kernel<<<dim3(2), dim3(128), 0, stream>>>(praw, ws);
    table_kernel<<<dim3(64), dim3(128), 0, stream>>>(ws, rm_bf, cm_bf);
    out_kernel<<<dim3(4096), dim3(256), 0, stream>>>(tt, tv, np, embed, rm_bf, cm_bf, out);
}

// Round 2
// 59.890 us; speedup vs baseline: 1.7348x; 1.7348x over previous
//
#include <hip/hip_runtime.h>
#include <hip/hip_bf16.h>
#include <stdint.h>

typedef __attribute__((ext_vector_type(4))) float fx4;
typedef __attribute__((ext_vector_type(8))) short bx8;
typedef unsigned short u16;
typedef unsigned int u32;

#define LDW 72   // LDS row stride in u16: 144B -> bank stride 4 dwords -> 2-way max (free)

// ws layout (bytes):
//   u16 planes[4][2][4096] @ 0      : rmT_hi, rmT_lo, cmT_hi, cmT_lo  (per generator)  = 64 KiB
//   u16 rm_bf[64][4096]    @ 65536                                                      = 512 KiB
//   u16 cm_bf[64][4096]    @ 65536+524288                                               = 512 KiB

__device__ __forceinline__ u16 f2bf(float x) {
    u32 u = __float_as_uint(x);
    return (u16)((u + 0x7FFFu + ((u >> 16) & 1u)) >> 16);
}
__device__ __forceinline__ float bf2f(u16 h) { return __uint_as_float(((u32)h) << 16); }

__device__ __forceinline__ bx8 ldf(const u16* p, int R, int kb) {
    return *(const bx8*)(p + R * LDW + kb);
}

__device__ __forceinline__ fx4 mm3(bx8 ah, bx8 al, bx8 bh, bx8 bl, fx4 c) {
    c = __builtin_amdgcn_mfma_f32_16x16x32_bf16(ah, bh, c, 0, 0, 0);
    c = __builtin_amdgcn_mfma_f32_16x16x32_bf16(ah, bl, c, 0, 0, 0);
    c = __builtin_amdgcn_mfma_f32_16x16x32_bf16(al, bh, c, 0, 0, 0);
    return c;
}

// G = (Z1 rows) x (Z2^T); tiles (w, ct), ct = 0..3. acc[ct] = 16x16 C-frag (fx4/lane).
__device__ __forceinline__ void mm_single(const u16* z1h, const u16* z1l,
                                          const u16* z2h, const u16* z2l,
                                          int w, int l, fx4 acc[4]) {
    const int lr = l & 15, k8 = (l >> 4) * 8;
    const int ra = w * 16 + lr;
    bx8 a0h = ldf(z1h, ra, k8),      a0l = ldf(z1l, ra, k8);
    bx8 a1h = ldf(z1h, ra, 32 + k8), a1l = ldf(z1l, ra, 32 + k8);
#pragma unroll
    for (int ct = 0; ct < 4; ++ct) {
        const int rb = ct * 16 + lr;
        bx8 b0h = ldf(z2h, rb, k8),      b0l = ldf(z2l, rb, k8);
        bx8 b1h = ldf(z2h, rb, 32 + k8), b1l = ldf(z2l, rb, 32 + k8);
        fx4 c = {0.f, 0.f, 0.f, 0.f};
        c = mm3(a0h, a0l, b0h, b0l, c);
        c = mm3(a1h, a1l, b1h, b1l, c);
        acc[ct] = c;
    }
}

// G1 = (Zcm rows) x (Zrm^T),  G2 = (Zrm rows) x (Zcm^T).  Tile order ct = (w+i)&3 so the
// wave's own A-frags are the i==0 B-loads (no redundant reads, no dynamic indexing).
__device__ __forceinline__ void mm_dual(const u16* cmh, const u16* cml,
                                        const u16* rmh, const u16* rml,
                                        int w, int l, fx4 acc1[4], fx4 acc2[4], int cts[4]) {
    const int lr = l & 15, k8 = (l >> 4) * 8;
    bx8 ac0h, ac0l, ac1h, ac1l, ar0h, ar0l, ar1h, ar1l;
#pragma unroll
    for (int i = 0; i < 4; ++i) {
        const int ct = (w + i) & 3;
        cts[i] = ct;
        const int rb = ct * 16 + lr;
        bx8 bc0h = ldf(cmh, rb, k8),      bc0l = ldf(cml, rb, k8);
        bx8 bc1h = ldf(cmh, rb, 32 + k8), bc1l = ldf(cml, rb, 32 + k8);
        bx8 br0h = ldf(rmh, rb, k8),      br0l = ldf(rml, rb, k8);
        bx8 br1h = ldf(rmh, rb, 32 + k8), br1l = ldf(rml, rb, 32 + k8);
        if (i == 0) { ac0h = bc0h; ac0l = bc0l; ac1h = bc1h; ac1l = bc1l;
                      ar0h = br0h; ar0l = br0l; ar1h = br1h; ar1l = br1l; }
        fx4 c1 = {0.f, 0.f, 0.f, 0.f}, c2 = {0.f, 0.f, 0.f, 0.f};
        c1 = mm3(ac0h, ac0l, br0h, br0l, c1);
        c1 = mm3(ac1h, ac1l, br1h, br1l, c1);
        c2 = mm3(ar0h, ar0l, bc0h, bc0l, c2);
        c2 = mm3(ar1h, ar1l, bc1h, bc1l, c2);
        acc1[i] = c1; acc2[i] = c2;
    }
}

// Store C-frag tile into hi/lo LDS planes; C layout writes are contiguous along rows of the
// array (cm of G), i.e. producing G fills array(G^T rm).
__device__ __forceinline__ void st_hl(u16* hi, u16* lo, int w, int ct, int l, fx4 a) {
    const int Ar = ct * 16 + (l & 15), Ac = w * 16 + 4 * (l >> 4);
    union { u16 u[4]; uint2 v; } H, L;
#pragma unroll
    for (int r = 0; r < 4; ++r) {
        u16 h = f2bf(a[r]);
        H.u[r] = h;
        L.u[r] = f2bf(a[r] - bf2f(h));
    }
    *(uint2*)(hi + Ar * LDW + Ac) = H.v;
    *(uint2*)(lo + Ar * LDW + Ac) = L.v;
}

// Store C-frag tile as rounded bf16 into a global [64][64] u16 table.
__device__ __forceinline__ void st_bf(u16* T, int w, int ct, int l, fx4 a) {
    const int Ar = ct * 16 + (l & 15), Ac = w * 16 + 4 * (l >> 4);
    union { u16 u[4]; uint2 v; } pk;
#pragma unroll
    for (int r = 0; r < 4; ++r) pk.u[r] = f2bf(a[r]);
    *(uint2*)(T + Ar * 64 + Ac) = pk.v;
}

// Epilogues for the Horner steps; M = (P - P^T)/64 recomputed from global P (L1-hot).
// epiT: G += (qa I + qb M)^T at tile (w, ct)   [for G = (R*M2 + E)^T]
__device__ __forceinline__ void epiT(fx4& a, const float* __restrict__ P,
                                     int w, int ct, int l, float qa, float qb) {
    const int col = ct * 16 + (l & 15), row0 = w * 16 + 4 * (l >> 4);
#pragma unroll
    for (int r = 0; r < 4; ++r) {
        const int row = row0 + r;
        float m = (P[col * 64 + row] - P[row * 64 + col]) * 0.015625f;  // M[col][row]
        a[r] += qb * m + (row == col ? qa : 0.f);
    }
}
// epiN: G += qa I + qb M at tile (w, ct)       [for G = R*M2 + E]
__device__ __forceinline__ void epiN(fx4& a, const float* __restrict__ P,
                                     int w, int ct, int l, float qa, float qb) {
    const int col = ct * 16 + (l & 15), row0 = w * 16 + 4 * (l >> 4);
#pragma unroll
    for (int r = 0; r < 4; ++r) {
        const int row = row0 + r;
        float m = (P[row * 64 + col] - P[col * 64 + row]) * 0.015625f;  // M[row][col]
        a[r] += qb * m + (row == col ? qa : 0.f);
    }
}

// K1: expm(P - P^T) per generator via scaling(1/64)+Taylor13+6 squarings, all bf16x3 MFMA.
__global__ __launch_bounds__(256) void expm_kernel(const float* __restrict__ praw,
                                                   u16* __restrict__ wsP)
{
    __shared__ u16 Xh[64 * LDW], Xl[64 * LDW];   // state rm plane (init: rm(M))
    __shared__ u16 Yh[64 * LDW], Yl[64 * LDW];   // state cm plane (init: cm(M))
    __shared__ u16 Qh[64 * LDW], Ql[64 * LDW];   // M2 (symmetric)
    const int g = blockIdx.x, tid = threadIdx.x;
    const int w = tid >> 6, l = tid & 63;
    const float* P = praw + g * 4096;

    // build M planes
    for (int s = tid; s < 4096; s += 256) {
        const int r = s >> 6, c = s & 63;
        const float m = (P[r * 64 + c] - P[c * 64 + r]) * 0.015625f;
        u16 h = f2bf(m);
        Xh[r * LDW + c] = h; Xl[r * LDW + c] = f2bf(m - bf2f(h));
        u16 h2 = f2bf(-m);
        Yh[r * LDW + c] = h2; Yl[r * LDW + c] = f2bf(-m - bf2f(h2));
    }
    __syncthreads();

    fx4 acc[4], a1[4], a2[4]; int cts[4];

    // M2 = M@M  (G = M^T M^T = M2^T = M2, symmetric)
    mm_single(Yh, Yl, Xh, Xl, w, l, acc);
    __syncthreads();   // all reads of X,Y done before overwriting X below
#pragma unroll
    for (int ct = 0; ct < 4; ++ct) st_hl(Qh, Ql, w, ct, l, acc[ct]);
    // Horner init (in place on X): R = C12 I + C13 M
    {
        const float C12f = (float)(1.0 / 479001600.0);
        const float C13f = (float)(1.0 / 6227020800.0);
        for (int s = tid; s < 4096; s += 256) {
            const int r = s >> 6, c = s & 63;
            float m = bf2f(Xh[r * LDW + c]) + bf2f(Xl[r * LDW + c]);
            float v = C13f * m + (r == c ? C12f : 0.f);
            u16 h = f2bf(v);
            Xh[r * LDW + c] = h; Xl[r * LDW + c] = f2bf(v - bf2f(h));
        }
    }
    __syncthreads();

    // 5 single Horner steps i = 5..1: R <- R*M2 + C[2i] I + C[2i+1] M   (computed as G = R'^T)
#pragma unroll
    for (int i = 5; i >= 1; --i) {
        const float qa = (i == 5) ? (float)(1.0 / 3628800.0)
                       : (i == 4) ? (float)(1.0 / 40320.0)
                       : (i == 3) ? (float)(1.0 / 720.0)
                       : (i == 2) ? (float)(1.0 / 24.0)
                       :            0.5f;
        const float qb = (i == 5) ? (float)(1.0 / 39916800.0)
                       : (i == 4) ? (float)(1.0 / 362880.0)
                       : (i == 3) ? (float)(1.0 / 5040.0)
                       : (i == 2) ? (float)(1.0 / 120.0)
                       :            (float)(1.0 / 6.0);
        mm_single(Qh, Ql, Xh, Xl, w, l, acc);
#pragma unroll
        for (int ct = 0; ct < 4; ++ct) epiT(acc[ct], P, w, ct, l, qa, qb);
        __syncthreads();
#pragma unroll
        for (int ct = 0; ct < 4; ++ct) st_hl(Xh, Xl, w, ct, l, acc[ct]);
        __syncthreads();
    }

    // last Horner step i=0 (dual): X <- rm(R_final), Y <- cm(R_final)
    mm_dual(Qh, Ql, Xh, Xl, w, l, a1, a2, cts);
#pragma unroll
    for (int i = 0; i < 4; ++i) {
        epiT(a1[i], P, w, cts[i], l, 1.f, 1.f);
        epiN(a2[i], P, w, cts[i], l, 1.f, 1.f);
    }
    __syncthreads();
#pragma unroll
    for (int i = 0; i < 4; ++i) {
        st_hl(Xh, Xl, w, cts[i], l, a1[i]);
        st_hl(Yh, Yl, w, cts[i], l, a2[i]);
    }
    __syncthreads();

    // 6 squarings: (rm,cm) <- (rm,cm) of R^2
#pragma unroll 1
    for (int s6 = 0; s6 < 6; ++s6) {
        mm_dual(Yh, Yl, Xh, Xl, w, l, a1, a2, cts);
        __syncthreads();
#pragma unroll
        for (int i = 0; i < 4; ++i) {
            st_hl(Xh, Xl, w, cts[i], l, a1[i]);
            st_hl(Yh, Yl, w, cts[i], l, a2[i]);
        }
        __syncthreads();
    }

    // T = R^T:  rm(T) = cm(R) = Y,  cm(T) = rm(R) = X.  Store planes (semantic 64-stride).
    for (int s8 = tid; s8 < 512; s8 += 256) {
        const int base = s8 * 8, r = base >> 6, c = base & 63;
        *(uint4*)(wsP + 0 * 8192 + g * 4096 + base) = *(const uint4*)(Yh + r * LDW + c);
        *(uint4*)(wsP + 1 * 8192 + g * 4096 + base) = *(const uint4*)(Yl + r * LDW + c);
        *(uint4*)(wsP + 2 * 8192 + g * 4096 + base) = *(const uint4*)(Xh + r * LDW + c);
        *(uint4*)(wsP + 3 * 8192 + g * 4096 + base) = *(const uint4*)(Xl + r * LDW + c);
    }
}

// K2: chain tables E(p) for p in [0,64), bf16x3 MFMA, one block per p.
__global__ __launch_bounds__(256) void table_kernel(const u16* __restrict__ wsP,
                                                    u16* __restrict__ rm_bf,
                                                    u16* __restrict__ cm_bf)
{
    __shared__ u16 TAh[64 * LDW], TAl[64 * LDW];  // cm(T0)
    __shared__ u16 TBh[64 * LDW], TBl[64 * LDW];  // cm(T1)
    __shared__ u16 Eh[64 * LDW],  El[64 * LDW];   // rm(E)
    const int p = blockIdx.x, tid = threadIdx.x;
    const int w = tid >> 6, l = tid & 63;

    if (p < 2) {
        for (int s = tid; s < 4096; s += 256) {
            u16 v = ((s >> 6) == (s & 63)) ? (u16)0x3F80 : (u16)0;
            rm_bf[p * 4096 + s] = v;
            cm_bf[p * 4096 + s] = v;
        }
        return;
    }
    const int d = 31 - __clz(p);

    for (int s8 = tid; s8 < 512; s8 += 256) {
        const int base = s8 * 8, r = base >> 6, c = base & 63;
        *(uint4*)(TAh + r * LDW + c) = *(const uint4*)(wsP + 2 * 8192 + 0 * 4096 + base);
        *(uint4*)(TAl + r * LDW + c) = *(const uint4*)(wsP + 3 * 8192 + 0 * 4096 + base);
        *(uint4*)(TBh + r * LDW + c) = *(const uint4*)(wsP + 2 * 8192 + 1 * 4096 + base);
        *(uint4*)(TBl + r * LDW + c) = *(const uint4*)(wsP + 3 * 8192 + 1 * 4096 + base);
    }
    if (d == 1) {
        for (int s = tid; s < 4096; s += 256) {
            const int r = s >> 6, c = s & 63;
            Eh[r * LDW + c] = (r == c) ? (u16)0x3F80 : (u16)0;
            El[r * LDW + c] = 0;
        }
    } else {
        const int b0 = p & 1;
        for (int s8 = tid; s8 < 512; s8 += 256) {
            const int base = s8 * 8, r = base >> 6, c = base & 63;
            *(uint4*)(Eh + r * LDW + c) = *(const uint4*)(wsP + 0 * 8192 + b0 * 4096 + base);
            *(uint4*)(El + r * LDW + c) = *(const uint4*)(wsP + 1 * 8192 + b0 * 4096 + base);
        }
    }
    __syncthreads();

    fx4 acc[4], a1[4], a2[4]; int cts[4];

    // single steps j = 1..d-2:  E <- E * T[b_j]   (G = E'^T -> rm(E'))
    for (int j = 1; j <= d - 2; ++j) {
        const int b = (p >> j) & 1;
        const u16* th = b ? TBh : TAh;
        const u16* tl = b ? TBl : TAl;
        mm_single(th, tl, Eh, El, w, l, acc);
        __syncthreads();
#pragma unroll
        for (int ct = 0; ct < 4; ++ct) st_hl(Eh, El, w, ct, l, acc[ct]);
        __syncthreads();
    }

    // final dual step j = d-1: write bf16 tables (rm and cm) directly
    {
        const int b = (p >> (d - 1)) & 1;
        const u16* th = b ? TBh : TAh;
        const u16* tl = b ? TBl : TAl;
        mm_dual(th, tl, Eh, El, w, l, a1, a2, cts);
#pragma unroll
        for (int i = 0; i < 4; ++i) {
            st_bf(rm_bf + p * 4096, w, cts[i], l, a1[i]);
            st_bf(cm_bf + p * 4096, w, cts[i], l, a2[i]);
        }
    }
}

// K3: per-token output: content + maps (table copy or maps^T = E_hi^T * E_lo^T via MFMA,
// giving contiguous dwordx4 stores).
__global__ __launch_bounds__(256) void out_kernel(const int* __restrict__ tt,
                                                  const int* __restrict__ tv,
                                                  const int* __restrict__ npos,
                                                  const float* __restrict__ embed,
                                                  const u16* __restrict__ rm_bf,
                                                  const u16* __restrict__ cm_bf,
                                                  float* __restrict__ out)
{
    const int flat = blockIdx.x, tid = threadIdx.x;
    const int pos = npos[flat];

    if (tid < 64) {
        const int t = tt[flat], v = tv[flat];
        int idx; bool valid = true;
        if (t == 0)      idx = 0;
        else if (t == 1) idx = v + 1;
        else if (t == 2) idx = v + 5;
        else if (t == 4) idx = 8;
        else if (t == 3 && v == -1) idx = 10;
        else { idx = 0; valid = false; }
        out[flat * 64 + tid] = valid ? embed[idx * 64 + tid] : 0.f;
    }

    float* om = out + 4096 * 64 + (size_t)flat * 4096;

    if (pos < 64) {
        const u16* src = rm_bf + pos * 4096;
        for (int e = tid * 8; e < 4096; e += 256 * 8) {
            uint4 ld = *(const uint4*)(src + e);
            fx4 lo, hi;
            lo[0] = __uint_as_float(ld.x << 16); lo[1] = __uint_as_float(ld.x & 0xFFFF0000u);
            lo[2] = __uint_as_float(ld.y << 16); lo[3] = __uint_as_float(ld.y & 0xFFFF0000u);
            hi[0] = __uint_as_float(ld.z << 16); hi[1] = __uint_as_float(ld.z & 0xFFFF0000u);
            hi[2] = __uint_as_float(ld.w << 16); hi[3] = __uint_as_float(ld.w & 0xFFFF0000u);
            *(fx4*)(om + e) = lo;
            *(fx4*)(om + e + 4) = hi;
        }
    } else {
        const int lo5 = (pos & 31) | 32;
        const int hi5 = pos >> 5;
        const u16* Acm = cm_bf + hi5 * 4096;   // A = E_hi^T
        const u16* Brm = rm_bf + lo5 * 4096;   // B = E_lo^T
        const int w = tid >> 6, l = tid & 63;
        const int lr = l & 15, k8 = (l >> 4) * 8;

        bx8 a0 = *(const bx8*)(Acm + (w * 16 + lr) * 64 + k8);
        bx8 a1 = *(const bx8*)(Acm + (w * 16 + lr) * 64 + 32 + k8);
#pragma unroll
        for (int ct = 0; ct < 4; ++ct) {
            bx8 b0 = *(const bx8*)(Brm + (ct * 16 + lr) * 64 + k8);
            bx8 b1 = *(const bx8*)(Brm + (ct * 16 + lr) * 64 + 32 + k8);
            fx4 c = {0.f, 0.f, 0.f, 0.f};
            c = __builtin_amdgcn_mfma_f32_16x16x32_bf16(a0, b0, c, 0, 0, 0);
            c = __builtin_amdgcn_mfma_f32_16x16x32_bf16(a1, b1, c, 0, 0, 0);
            // G = maps^T tile (w,ct): lane holds maps[ct*16+lr][w*16+4*(l>>4)+r], r consecutive
            const int Ar = ct * 16 + lr, Ac = w * 16 + 4 * (l >> 4);
            *(fx4*)(om + Ar * 64 + Ac) = c;
        }
    }
}

extern "C" void kernel_launch(void* const* d_in, const int* in_sizes, int n_in,
                              void* d_out, int out_size, void* d_ws, size_t ws_size,
                              hipStream_t stream)
{
    const int*   tt    = (const int*)d_in[0];
    const int*   tv    = (const int*)d_in[1];
    const int*   np    = (const int*)d_in[2];
    const float* embed = (const float*)d_in[3];
    const float* praw  = (const float*)d_in[4];
    float* out = (float*)d_out;

    u16* wsP   = (u16*)d_ws;
    u16* rm_bf = (u16*)((char*)d_ws + 65536);
    u16* cm_bf = (u16*)((char*)d_ws + 65536 + 524288);

    expm_kernel<<<dim3(2), dim3(256), 0, stream>>>(praw, wsP);
    table_kernel<<<dim3(64), dim3(256), 0, stream>>>(wsP, rm_bf, cm_bf);
    out_kernel<<<dim3(4096), dim3(256), 0, stream>>>(tt, tv, np, embed, rm_bf, cm_bf, out);
}

// Round 3
// 49.675 us; speedup vs baseline: 2.0916x; 1.2056x over previous
//
#include <hip/hip_runtime.h>
#include <hip/hip_bf16.h>
#include <stdint.h>

typedef __attribute__((ext_vector_type(4))) float fx4;
typedef __attribute__((ext_vector_type(8))) short bx8;
typedef unsigned short u16;
typedef unsigned int u32;

#define LDW 72   // LDS row stride in u16: 144B -> bank stride 4 -> 2-way max (free)

// ws layout (bytes):
//   u16 planes[4][2][4096] @ 0      : rmT_hi, rmT_lo, cmT_hi, cmT_lo  (per generator) = 64 KiB
//   u16 rm_bf[64][4096]    @ 65536                                                     = 512 KiB
//   u16 cm_bf[64][4096]    @ 65536+524288                                              = 512 KiB

__device__ __forceinline__ u16 f2bf(float x) {
    u32 u = __float_as_uint(x);
    return (u16)((u + 0x7FFFu + ((u >> 16) & 1u)) >> 16);
}
__device__ __forceinline__ float bf2f(u16 h) { return __uint_as_float(((u32)h) << 16); }

__device__ __forceinline__ bx8 ldf(const u16* p, int R, int kb) {
    return *(const bx8*)(p + R * LDW + kb);
}

__device__ __forceinline__ fx4 mm3(bx8 ah, bx8 al, bx8 bh, bx8 bl, fx4 c) {
    c = __builtin_amdgcn_mfma_f32_16x16x32_bf16(ah, bh, c, 0, 0, 0);
    c = __builtin_amdgcn_mfma_f32_16x16x32_bf16(ah, bl, c, 0, 0, 0);
    c = __builtin_amdgcn_mfma_f32_16x16x32_bf16(al, bh, c, 0, 0, 0);
    return c;
}

// 8-wave mapping: wave w -> row-stripe wq = w&3, tile-pair ch = w>>2 (cts {2ch, 2ch+1}).
// G = (Z1 rows) x (Z2 rows)^T for the wave's 2 tiles.
__device__ __forceinline__ void mm_single8(const u16* z1h, const u16* z1l,
                                           const u16* z2h, const u16* z2l,
                                           int wq, int ch, int l, fx4 acc[2]) {
    const int lr = l & 15, k8 = (l >> 4) * 8, ra = wq * 16 + lr;
    bx8 a0h = ldf(z1h, ra, k8),      a0l = ldf(z1l, ra, k8);
    bx8 a1h = ldf(z1h, ra, 32 + k8), a1l = ldf(z1l, ra, 32 + k8);
#pragma unroll
    for (int i = 0; i < 2; ++i) {
        const int rb = (ch * 2 + i) * 16 + lr;
        bx8 b0h = ldf(z2h, rb, k8),      b0l = ldf(z2l, rb, k8);
        bx8 b1h = ldf(z2h, rb, 32 + k8), b1l = ldf(z2l, rb, 32 + k8);
        fx4 c = {0.f, 0.f, 0.f, 0.f};
        c = mm3(a0h, a0l, b0h, b0l, c);
        c = mm3(a1h, a1l, b1h, b1l, c);
        acc[i] = c;
    }
}

// G1 = (cm rows) x (rm rows)^T,  G2 = (rm rows) x (cm rows)^T  (both for the wave's tiles)
__device__ __forceinline__ void mm_dual8(const u16* cmh, const u16* cml,
                                         const u16* rmh, const u16* rml,
                                         int wq, int ch, int l, fx4 a1[2], fx4 a2[2]) {
    const int lr = l & 15, k8 = (l >> 4) * 8, ra = wq * 16 + lr;
    bx8 ac0h = ldf(cmh, ra, k8),      ac0l = ldf(cml, ra, k8);
    bx8 ac1h = ldf(cmh, ra, 32 + k8), ac1l = ldf(cml, ra, 32 + k8);
    bx8 ar0h = ldf(rmh, ra, k8),      ar0l = ldf(rml, ra, k8);
    bx8 ar1h = ldf(rmh, ra, 32 + k8), ar1l = ldf(rml, ra, 32 + k8);
#pragma unroll
    for (int i = 0; i < 2; ++i) {
        const int rb = (ch * 2 + i) * 16 + lr;
        bx8 bc0h = ldf(cmh, rb, k8),      bc0l = ldf(cml, rb, k8);
        bx8 bc1h = ldf(cmh, rb, 32 + k8), bc1l = ldf(cml, rb, 32 + k8);
        bx8 br0h = ldf(rmh, rb, k8),      br0l = ldf(rml, rb, k8);
        bx8 br1h = ldf(rmh, rb, 32 + k8), br1l = ldf(rml, rb, 32 + k8);
        fx4 c1 = {0.f, 0.f, 0.f, 0.f}, c2 = {0.f, 0.f, 0.f, 0.f};
        c1 = mm3(ac0h, ac0l, br0h, br0l, c1);
        c1 = mm3(ac1h, ac1l, br1h, br1l, c1);
        c2 = mm3(ar0h, ar0l, bc0h, bc0l, c2);
        c2 = mm3(ar1h, ar1l, bc1h, bc1l, c2);
        a1[i] = c1; a2[i] = c2;
    }
}

// Store C-frag tile into hi/lo LDS planes (array gets G^T, i.e. producing G fills rm(G^T)).
// hi = truncation (exact residual), lo = rounded residual.
__device__ __forceinline__ void st_hl(u16* hi, u16* lo, int wq, int ct, int l, fx4 a) {
    const int Ar = ct * 16 + (l & 15), Ac = wq * 16 + 4 * (l >> 4);
    union { u16 u[4]; uint2 v; } H, L;
#pragma unroll
    for (int r = 0; r < 4; ++r) {
        u32 u = __float_as_uint(a[r]);
        H.u[r] = (u16)(u >> 16);
        L.u[r] = f2bf(a[r] - __uint_as_float(u & 0xFFFF0000u));
    }
    *(uint2*)(hi + Ar * LDW + Ac) = H.v;
    *(uint2*)(lo + Ar * LDW + Ac) = L.v;
}

// Store C-frag tile as rounded bf16 into a global [64][64] u16 table.
__device__ __forceinline__ void st_bf(u16* T, int wq, int ct, int l, fx4 a) {
    const int Ar = ct * 16 + (l & 15), Ac = wq * 16 + 4 * (l >> 4);
    union { u16 u[4]; uint2 v; } pk;
#pragma unroll
    for (int r = 0; r < 4; ++r) pk.u[r] = f2bf(a[r]);
    *(uint2*)(T + Ar * 64 + Ac) = pk.v;
}

// epiT: G += (qa I + qb M)^T   (M = (P-P^T)/64 recomputed from global P, L1-hot)
__device__ __forceinline__ void epiT(fx4& a, const float* __restrict__ P,
                                     int wq, int ct, int l, float qa, float qb) {
    const int col = ct * 16 + (l & 15), row0 = wq * 16 + 4 * (l >> 4);
#pragma unroll
    for (int r = 0; r < 4; ++r) {
        const int row = row0 + r;
        float m = (P[col * 64 + row] - P[row * 64 + col]) * 0.015625f;  // M[col][row]
        a[r] += qb * m + (row == col ? qa : 0.f);
    }
}
// epiN: G += qa I + qb M
__device__ __forceinline__ void epiN(fx4& a, const float* __restrict__ P,
                                     int wq, int ct, int l, float qa, float qb) {
    const int col = ct * 16 + (l & 15), row0 = wq * 16 + 4 * (l >> 4);
#pragma unroll
    for (int r = 0; r < 4; ++r) {
        const int row = row0 + r;
        float m = (P[row * 64 + col] - P[col * 64 + row]) * 0.015625f;  // M[row][col]
        a[r] += qb * m + (row == col ? qa : 0.f);
    }
}

// K1: expm(P - P^T) per generator: scale 1/64, degree-9 PS-Horner, 6 squarings. bf16x3 MFMA.
__global__ __launch_bounds__(512) void expm_kernel(const float* __restrict__ praw,
                                                   u16* __restrict__ wsP)
{
    __shared__ u16 Xh[64 * LDW], Xl[64 * LDW];   // state rm plane
    __shared__ u16 Yh[64 * LDW], Yl[64 * LDW];   // state cm plane
    __shared__ u16 Qh[64 * LDW], Ql[64 * LDW];   // M2 (symmetric)
    const int g = blockIdx.x, tid = threadIdx.x;
    const int w = tid >> 6, l = tid & 63;
    const int wq = w & 3, ch = w >> 2;
    const float* P = praw + g * 4096;

    // build M planes: X = rm(M), Y = cm(M) = rm(-M)
    for (int s = tid; s < 4096; s += 512) {
        const int r = s >> 6, c = s & 63;
        const float m = (P[r * 64 + c] - P[c * 64 + r]) * 0.015625f;
        u32 um = __float_as_uint(m);
        float lof = m - __uint_as_float(um & 0xFFFF0000u);
        Xh[r * LDW + c] = (u16)(um >> 16);
        Xl[r * LDW + c] = f2bf(lof);
        Yh[r * LDW + c] = (u16)((um ^ 0x80000000u) >> 16);
        Yl[r * LDW + c] = f2bf(-lof);
    }
    __syncthreads();

    fx4 acc[2], a1[2], a2[2];

    // M2 = M@M -> Q  (G = M^T M^T = M2^T = M2, symmetric)
    mm_single8(Yh, Yl, Xh, Xl, wq, ch, l, acc);
    __syncthreads();   // all X/Y reads done before X rewrite below
    st_hl(Qh, Ql, wq, ch * 2, l, acc[0]);
    st_hl(Qh, Ql, wq, ch * 2 + 1, l, acc[1]);
    // Horner init in place on X: R = C8 I + C9 M
    {
        const float C8 = (float)(1.0 / 40320.0), C9 = (float)(1.0 / 362880.0);
        for (int s = tid; s < 4096; s += 512) {
            const int r = s >> 6, c = s & 63;
            float m = bf2f(Xh[r * LDW + c]) + bf2f(Xl[r * LDW + c]);
            float v = C9 * m + (r == c ? C8 : 0.f);
            u32 u = __float_as_uint(v);
            Xh[r * LDW + c] = (u16)(u >> 16);
            Xl[r * LDW + c] = f2bf(v - __uint_as_float(u & 0xFFFF0000u));
        }
    }
    __syncthreads();

    // 3 single Horner steps: R <- R*M2 + qa I + qb M   (computed as G = R'^T)
    const float QA[3] = { (float)(1.0 / 720.0), (float)(1.0 / 24.0), 0.5f };
    const float QB[3] = { (float)(1.0 / 5040.0), (float)(1.0 / 120.0), (float)(1.0 / 6.0) };
#pragma unroll
    for (int i = 0; i < 3; ++i) {
        mm_single8(Qh, Ql, Xh, Xl, wq, ch, l, acc);
        epiT(acc[0], P, wq, ch * 2, l, QA[i], QB[i]);
        epiT(acc[1], P, wq, ch * 2 + 1, l, QA[i], QB[i]);
        __syncthreads();
        st_hl(Xh, Xl, wq, ch * 2, l, acc[0]);
        st_hl(Xh, Xl, wq, ch * 2 + 1, l, acc[1]);
        __syncthreads();
    }

    // final Horner step (qa=qb=1), dual: X <- rm(R), Y <- cm(R)
    mm_dual8(Qh, Ql, Xh, Xl, wq, ch, l, a1, a2);
    epiT(a1[0], P, wq, ch * 2, l, 1.f, 1.f);  epiT(a1[1], P, wq, ch * 2 + 1, l, 1.f, 1.f);
    epiN(a2[0], P, wq, ch * 2, l, 1.f, 1.f);  epiN(a2[1], P, wq, ch * 2 + 1, l, 1.f, 1.f);
    __syncthreads();
    st_hl(Xh, Xl, wq, ch * 2, l, a1[0]);  st_hl(Xh, Xl, wq, ch * 2 + 1, l, a1[1]);
    st_hl(Yh, Yl, wq, ch * 2, l, a2[0]);  st_hl(Yh, Yl, wq, ch * 2 + 1, l, a2[1]);
    __syncthreads();

    // 6 squarings
#pragma unroll 1
    for (int s6 = 0; s6 < 6; ++s6) {
        mm_dual8(Yh, Yl, Xh, Xl, wq, ch, l, a1, a2);
        __syncthreads();
        st_hl(Xh, Xl, wq, ch * 2, l, a1[0]);  st_hl(Xh, Xl, wq, ch * 2 + 1, l, a1[1]);
        st_hl(Yh, Yl, wq, ch * 2, l, a2[0]);  st_hl(Yh, Yl, wq, ch * 2 + 1, l, a2[1]);
        __syncthreads();
    }

    // T = R^T: rm(T) = cm(R) = Y, cm(T) = rm(R) = X. Store planes dense (stride 64).
    for (int s8 = tid; s8 < 512; s8 += 512) {
        const int base = s8 * 8, r = base >> 6, c = base & 63;
        *(uint4*)(wsP + 0 * 8192 + g * 4096 + base) = *(const uint4*)(Yh + r * LDW + c);
        *(uint4*)(wsP + 1 * 8192 + g * 4096 + base) = *(const uint4*)(Yl + r * LDW + c);
        *(uint4*)(wsP + 2 * 8192 + g * 4096 + base) = *(const uint4*)(Xh + r * LDW + c);
        *(uint4*)(wsP + 3 * 8192 + g * 4096 + base) = *(const uint4*)(Xl + r * LDW + c);
    }
}

// K2: chain tables E(p) for p in [0,64), one block per p.
__global__ __launch_bounds__(512) void table_kernel(const u16* __restrict__ wsP,
                                                    u16* __restrict__ rm_bf,
                                                    u16* __restrict__ cm_bf)
{
    __shared__ u16 TAh[64 * LDW], TAl[64 * LDW];  // cm(T0)
    __shared__ u16 TBh[64 * LDW], TBl[64 * LDW];  // cm(T1)
    __shared__ u16 Eh[64 * LDW],  El[64 * LDW];   // rm(E)
    const int p = blockIdx.x, tid = threadIdx.x;
    const int w = tid >> 6, l = tid & 63;
    const int wq = w & 3, ch = w >> 2;

    if (p < 2) {
        for (int s = tid; s < 4096; s += 512) {
            u16 v = ((s >> 6) == (s & 63)) ? (u16)0x3F80 : (u16)0;
            rm_bf[p * 4096 + s] = v;
            cm_bf[p * 4096 + s] = v;
        }
        return;
    }
    const int d = 31 - __clz(p);

    {
        const int base = tid * 8, r = base >> 6, c = base & 63;
        *(uint4*)(TAh + r * LDW + c) = *(const uint4*)(wsP + 2 * 8192 + 0 * 4096 + base);
        *(uint4*)(TAl + r * LDW + c) = *(const uint4*)(wsP + 3 * 8192 + 0 * 4096 + base);
        *(uint4*)(TBh + r * LDW + c) = *(const uint4*)(wsP + 2 * 8192 + 1 * 4096 + base);
        *(uint4*)(TBl + r * LDW + c) = *(const uint4*)(wsP + 3 * 8192 + 1 * 4096 + base);
        if (d == 1) {
            for (int s = tid; s < 4096; s += 512) {
                const int rr = s >> 6, cc = s & 63;
                Eh[rr * LDW + cc] = (rr == cc) ? (u16)0x3F80 : (u16)0;
                El[rr * LDW + cc] = 0;
            }
        } else {
            const int b0 = p & 1;
            *(uint4*)(Eh + r * LDW + c) = *(const uint4*)(wsP + 0 * 8192 + b0 * 4096 + base);
            *(uint4*)(El + r * LDW + c) = *(const uint4*)(wsP + 1 * 8192 + b0 * 4096 + base);
        }
    }
    __syncthreads();

    fx4 acc[2], a1[2], a2[2];

    // single steps j = 1..d-2:  E <- E * T[b_j]
    for (int j = 1; j <= d - 2; ++j) {
        const int b = (p >> j) & 1;
        const u16* th = b ? TBh : TAh;
        const u16* tl = b ? TBl : TAl;
        mm_single8(th, tl, Eh, El, wq, ch, l, acc);
        __syncthreads();
        st_hl(Eh, El, wq, ch * 2, l, acc[0]);
        st_hl(Eh, El, wq, ch * 2 + 1, l, acc[1]);
        __syncthreads();
    }

    // final dual step j = d-1: write bf16 tables (rm and cm)
    {
        const int b = (p >> (d - 1)) & 1;
        const u16* th = b ? TBh : TAh;
        const u16* tl = b ? TBl : TAl;
        mm_dual8(th, tl, Eh, El, wq, ch, l, a1, a2);
#pragma unroll
        for (int i = 0; i < 2; ++i) {
            st_bf(rm_bf + p * 4096, wq, ch * 2 + i, l, a1[i]);
            st_bf(cm_bf + p * 4096, wq, ch * 2 + i, l, a2[i]);
        }
    }
}

// K3: one wave per token. Content row + maps (copy or full-register MFMA matmul).
__global__ __launch_bounds__(256) void out_kernel(const int* __restrict__ tt,
                                                  const int* __restrict__ tv,
                                                  const int* __restrict__ npos,
                                                  const float* __restrict__ embed,
                                                  const u16* __restrict__ rm_bf,
                                                  const u16* __restrict__ cm_bf,
                                                  float* __restrict__ out)
{
    const int tid = threadIdx.x;
    const int wv = tid >> 6, l = tid & 63;
    const int flat = blockIdx.x * 4 + wv;
    const int pos = npos[flat];

    {
        const int t = tt[flat], v = tv[flat];
        int idx; bool valid = true;
        if (t == 0)      idx = 0;
        else if (t == 1) idx = v + 1;
        else if (t == 2) idx = v + 5;
        else if (t == 4) idx = 8;
        else if (t == 3 && v == -1) idx = 10;
        else { idx = 0; valid = false; }
        out[flat * 64 + l] = valid ? embed[idx * 64 + l] : 0.f;
    }

    float* om = out + 4096 * 64 + (size_t)flat * 4096;

    if (pos < 64) {
        const u16* src = rm_bf + pos * 4096;
        for (int e = l * 8; e < 4096; e += 512) {
            uint4 ld = *(const uint4*)(src + e);
            fx4 lo, hi;
            lo[0] = __uint_as_float(ld.x << 16); lo[1] = __uint_as_float(ld.x & 0xFFFF0000u);
            lo[2] = __uint_as_float(ld.y << 16); lo[3] = __uint_as_float(ld.y & 0xFFFF0000u);
            hi[0] = __uint_as_float(ld.z << 16); hi[1] = __uint_as_float(ld.z & 0xFFFF0000u);
            hi[2] = __uint_as_float(ld.w << 16); hi[3] = __uint_as_float(ld.w & 0xFFFF0000u);
            __builtin_nontemporal_store(lo, (fx4*)(om + e));
            __builtin_nontemporal_store(hi, (fx4*)(om + e + 4));
        }
    } else {
        const int lo5 = (pos & 31) | 32;
        const int hi5 = pos >> 5;
        const u16* Acm = cm_bf + hi5 * 4096;   // A = E_hi^T
        const u16* Brm = rm_bf + lo5 * 4096;   // B = E_lo^T
        const int lr = l & 15, k8 = (l >> 4) * 8;

        bx8 A0[4], A1[4], B0[4], B1[4];
#pragma unroll
        for (int q = 0; q < 4; ++q) {
            A0[q] = *(const bx8*)(Acm + (q * 16 + lr) * 64 + k8);
            A1[q] = *(const bx8*)(Acm + (q * 16 + lr) * 64 + 32 + k8);
        }
#pragma unroll
        for (int c = 0; c < 4; ++c) {
            B0[c] = *(const bx8*)(Brm + (c * 16 + lr) * 64 + k8);
            B1[c] = *(const bx8*)(Brm + (c * 16 + lr) * 64 + 32 + k8);
        }
#pragma unroll
        for (int ct = 0; ct < 4; ++ct) {
#pragma unroll
            for (int q = 0; q < 4; ++q) {
                fx4 c4 = { 0.f, 0.f, 0.f, 0.f };
                c4 = __builtin_amdgcn_mfma_f32_16x16x32_bf16(A0[q], B0[ct], c4, 0, 0, 0);
                c4 = __builtin_amdgcn_mfma_f32_16x16x32_bf16(A1[q], B1[ct], c4, 0, 0, 0);
                // lane holds maps[ct*16+lr][q*16 + 4*(l>>4) + r], r = 0..3 contiguous
                __builtin_nontemporal_store(c4,
                    (fx4*)(om + (ct * 16 + lr) * 64 + q * 16 + 4 * (l >> 4)));
            }
        }
    }
}

extern "C" void kernel_launch(void* const* d_in, const int* in_sizes, int n_in,
                              void* d_out, int out_size, void* d_ws, size_t ws_size,
                              hipStream_t stream)
{
    const int*   tt    = (const int*)d_in[0];
    const int*   tv    = (const int*)d_in[1];
    const int*   np    = (const int*)d_in[2];
    const float* embed = (const float*)d_in[3];
    const float* praw  = (const float*)d_in[4];
    float* out = (float*)d_out;

    u16* wsP   = (u16*)d_ws;
    u16* rm_bf = (u16*)((char*)d_ws + 65536);
    u16* cm_bf = (u16*)((char*)d_ws + 65536 + 524288);

    expm_kernel<<<dim3(2), dim3(512), 0, stream>>>(praw, wsP);
    table_kernel<<<dim3(64), dim3(512), 0, stream>>>(wsP, rm_bf, cm_bf);
    out_kernel<<<dim3(1024), dim3(256), 0, stream>>>(tt, tv, np, embed, rm_bf, cm_bf, out);
}

// Round 4
// 48.511 us; speedup vs baseline: 2.1418x; 1.0240x over previous
//
#include <hip/hip_runtime.h>
#include <hip/hip_bf16.h>
#include <stdint.h>

typedef __attribute__((ext_vector_type(4))) float fx4;
typedef __attribute__((ext_vector_type(16))) float fx16;
typedef __attribute__((ext_vector_type(8))) short bx8;
typedef unsigned short u16;
typedef unsigned int u32;

#define LDW 72          // LDS row stride in u16 (144B): bank-uniform for our patterns
#define PL (64 * LDW)   // u16 per 64-row plane

// ws layout (bytes):
//   u16 wsP[2][4][4096] @ 0: per gen {rmT_hi, rmT_lo, cmT_hi, cmT_lo}, dense stride 64 (64 KiB)
//   u16 rm_bf[64][4096] @ 65536           (512 KiB)
//   u16 cm_bf[64][4096] @ 65536+524288    (512 KiB)

__device__ __forceinline__ u16 f2bf(float x) {
    u32 u = __float_as_uint(x);
    return (u16)((u + 0x7FFFu + ((u >> 16) & 1u)) >> 16);
}
__device__ __forceinline__ float bf2f(u16 h) { return __uint_as_float(((u32)h) << 16); }

// 32x32x16 A/B fragment load from a 64-row plane: band selects 32 rows.
// lane l: row = band*32 + (l&31), k-chunk kc: cols kc*16 + (l>>5)*8 .. +8
__device__ __forceinline__ bx8 ld32(const u16* p, int band, int kc, int l) {
    return *(const bx8*)(p + (band * 32 + (l & 31)) * LDW + kc * 16 + (l >> 5) * 8);
}

// G tile (ti,tj) = z1[rows ti-band] x z2[rows tj-band]^T, bf16x3 (hh + hl + lh), fp32 acc.
__device__ __forceinline__ void mmS(const u16* z1h, const u16* z1l,
                                    const u16* z2h, const u16* z2l,
                                    int ti, int tj, int l, fx16& acc) {
#pragma unroll
    for (int i = 0; i < 16; ++i) acc[i] = 0.f;
#pragma unroll
    for (int kc = 0; kc < 4; ++kc) {
        bx8 ah = ld32(z1h, ti, kc, l), al = ld32(z1l, ti, kc, l);
        bx8 bh = ld32(z2h, tj, kc, l), bl = ld32(z2l, tj, kc, l);
        acc = __builtin_amdgcn_mfma_f32_32x32x16_bf16(ah, bh, acc, 0, 0, 0);
        acc = __builtin_amdgcn_mfma_f32_32x32x16_bf16(ah, bl, acc, 0, 0, 0);
        acc = __builtin_amdgcn_mfma_f32_32x32x16_bf16(al, bh, acc, 0, 0, 0);
    }
}

// Dual: a1 = G1 tile (ti,tj) of z1 x z2^T;  a2 = G2 tile (tj,ti) of z2 x z1^T.
// G2's (tj,ti) tile reuses exactly G1's reads with A/B roles swapped -> same LDS traffic.
__device__ __forceinline__ void mmD(const u16* z1h, const u16* z1l,
                                    const u16* z2h, const u16* z2l,
                                    int ti, int tj, int l, fx16& a1, fx16& a2) {
#pragma unroll
    for (int i = 0; i < 16; ++i) { a1[i] = 0.f; a2[i] = 0.f; }
#pragma unroll
    for (int kc = 0; kc < 4; ++kc) {
        bx8 ah = ld32(z1h, ti, kc, l), al = ld32(z1l, ti, kc, l);
        bx8 bh = ld32(z2h, tj, kc, l), bl = ld32(z2l, tj, kc, l);
        a1 = __builtin_amdgcn_mfma_f32_32x32x16_bf16(ah, bh, a1, 0, 0, 0);
        a1 = __builtin_amdgcn_mfma_f32_32x32x16_bf16(ah, bl, a1, 0, 0, 0);
        a1 = __builtin_amdgcn_mfma_f32_32x32x16_bf16(al, bh, a1, 0, 0, 0);
        a2 = __builtin_amdgcn_mfma_f32_32x32x16_bf16(bh, ah, a2, 0, 0, 0);
        a2 = __builtin_amdgcn_mfma_f32_32x32x16_bf16(bh, al, a2, 0, 0, 0);
        a2 = __builtin_amdgcn_mfma_f32_32x32x16_bf16(bl, ah, a2, 0, 0, 0);
    }
}

// Store C-frag tile (TI=row-band, TJ=col-band) into hi/lo LDS planes as array(G^T).
// C layout: col = l&31, row = (reg&3) + 8*(reg>>2) + 4*(l>>5).
__device__ __forceinline__ void stP(u16* hi, u16* lo, int TI, int TJ, int l, const fx16& a) {
    const int Ar = TJ * 32 + (l & 31);
    const int c0 = TI * 32 + 4 * (l >> 5);
#pragma unroll
    for (int q = 0; q < 4; ++q) {
        union { u16 u[4]; uint2 v; } H, L;
#pragma unroll
        for (int r = 0; r < 4; ++r) {
            float v = a[4 * q + r];
            u32 u = __float_as_uint(v);
            H.u[r] = (u16)(u >> 16);
            L.u[r] = f2bf(v - __uint_as_float(u & 0xFFFF0000u));
        }
        *(uint2*)(hi + Ar * LDW + c0 + q * 8) = H.v;
        *(uint2*)(lo + Ar * LDW + c0 + q * 8) = L.v;
    }
}

// Store C-frag tile as rounded bf16 into a global [64][64] u16 table (array(G^T)).
__device__ __forceinline__ void stG(u16* T, int TI, int TJ, int l, const fx16& a) {
    const int Ar = TJ * 32 + (l & 31);
    const int c0 = TI * 32 + 4 * (l >> 5);
#pragma unroll
    for (int q = 0; q < 4; ++q) {
        union { u16 u[4]; uint2 v; } pk;
#pragma unroll
        for (int r = 0; r < 4; ++r) pk.u[r] = f2bf(a[4 * q + r]);
        *(uint2*)(T + Ar * 64 + c0 + q * 8) = pk.v;
    }
}

// epiT: G(tile TI,TJ) += (qa I + qb M)^T, M = (P - P^T)/32 from global P (L1-hot)
__device__ __forceinline__ void epiT32(fx16& a, const float* __restrict__ P,
                                       int TI, int TJ, int l, float qa, float qb) {
    const int gc = TJ * 32 + (l & 31);
    const int r0 = TI * 32 + 4 * (l >> 5);
#pragma unroll
    for (int q = 0; q < 4; ++q)
#pragma unroll
        for (int r = 0; r < 4; ++r) {
            const int gr = r0 + q * 8 + r;
            float m = (P[gc * 64 + gr] - P[gr * 64 + gc]) * 0.03125f;  // M[gc][gr]
            a[4 * q + r] += qb * m + (gr == gc ? qa : 0.f);
        }
}
// epiN: G(tile TI,TJ) += qa I + qb M
__device__ __forceinline__ void epiN32(fx16& a, const float* __restrict__ P,
                                       int TI, int TJ, int l, float qa, float qb) {
    const int gc = TJ * 32 + (l & 31);
    const int r0 = TI * 32 + 4 * (l >> 5);
#pragma unroll
    for (int q = 0; q < 4; ++q)
#pragma unroll
        for (int r = 0; r < 4; ++r) {
            const int gr = r0 + q * 8 + r;
            float m = (P[gr * 64 + gc] - P[gc * 64 + gr]) * 0.03125f;  // M[gr][gc]
            a[4 * q + r] += qb * m + (gr == gc ? qa : 0.f);
        }
}

// K1: expm(P - P^T): scale 1/32, degree-9 PS-Horner, 5 squarings. One barrier/step.
// Pairs: p0,p1,p2,p3. Schedule keeps每 step's write set disjoint from its read set.
__global__ __launch_bounds__(256) void expm_kernel(const float* __restrict__ praw,
                                                   u16* __restrict__ wsP)
{
    __shared__ u16 S[8 * PL];   // 4 hi/lo pairs = 73.7 KB
    const int g = blockIdx.x, tid = threadIdx.x;
    const int w = tid >> 6, l = tid & 63;
    const int ti = w & 1, tj = w >> 1;
    const float* P = praw + g * 4096;

    u16* p0h = S;            u16* p0l = S + PL;
    u16* p1h = S + 2 * PL;   u16* p1l = S + 3 * PL;
    u16* p2h = S + 4 * PL;   u16* p2l = S + 5 * PL;
    u16* p3h = S + 6 * PL;   u16* p3l = S + 7 * PL;

    // build: p0 = rm(M), p1 = cm(M)
    for (int s = tid; s < 4096; s += 256) {
        const int r = s >> 6, c = s & 63;
        const float m = (P[r * 64 + c] - P[c * 64 + r]) * 0.03125f;
        u32 um = __float_as_uint(m);
        float lof = m - __uint_as_float(um & 0xFFFF0000u);
        u16 hh = (u16)(um >> 16), ll = f2bf(lof);
        p0h[r * LDW + c] = hh;  p0l[r * LDW + c] = ll;
        p1h[c * LDW + r] = hh;  p1l[c * LDW + r] = ll;
    }
    __syncthreads();

    fx16 acc, a1, a2;

    // step0: Q = M2 -> p2 (G = M^T M^T = M2 symmetric); R0 = C8 I + C9 M -> p3
    mmS(p1h, p1l, p0h, p0l, ti, tj, l, acc);
    stP(p2h, p2l, ti, tj, l, acc);
    {
        const float C8 = 2.48015873015873e-5f, C9 = 2.75573192239859e-6f;
        for (int s = tid; s < 4096; s += 256) {
            const int r = s >> 6, c = s & 63;
            float m = bf2f(p0h[r * LDW + c]) + bf2f(p0l[r * LDW + c]);
            float v = C9 * m + (r == c ? C8 : 0.f);
            u32 u = __float_as_uint(v);
            p3h[r * LDW + c] = (u16)(u >> 16);
            p3l[r * LDW + c] = f2bf(v - __uint_as_float(u & 0xFFFF0000u));
        }
    }
    __syncthreads();

    // H1: read(p2,p3) -> p0
    mmS(p2h, p2l, p3h, p3l, ti, tj, l, acc);
    epiT32(acc, P, ti, tj, l, 1.388888888888889e-3f, 1.984126984126984e-4f); // 1/720, 1/5040
    stP(p0h, p0l, ti, tj, l, acc);
    __syncthreads();
    // H2: read(p2,p0) -> p3
    mmS(p2h, p2l, p0h, p0l, ti, tj, l, acc);
    epiT32(acc, P, ti, tj, l, 4.166666666666667e-2f, 8.333333333333333e-3f); // 1/24, 1/120
    stP(p3h, p3l, ti, tj, l, acc);
    __syncthreads();
    // H3: read(p2,p3) -> p0
    mmS(p2h, p2l, p3h, p3l, ti, tj, l, acc);
    epiT32(acc, P, ti, tj, l, 0.5f, 1.666666666666667e-1f);                  // 1/2, 1/6
    stP(p0h, p0l, ti, tj, l, acc);
    __syncthreads();
    // H-final (dual): read(p2,p0) -> X:p3 = rm(R), Y:p1 = cm(R)
    mmD(p2h, p2l, p0h, p0l, ti, tj, l, a1, a2);
    epiT32(a1, P, ti, tj, l, 1.f, 1.f);
    epiN32(a2, P, tj, ti, l, 1.f, 1.f);
    stP(p3h, p3l, ti, tj, l, a1);
    stP(p1h, p1l, tj, ti, l, a2);
    __syncthreads();

    // 5 squarings: (X,Y) <- (rm,cm) of R^2; ping-pong (p3,p1) <-> (p0,p2)
    u16 *Ych = p1h, *Ycl = p1l, *Xch = p3h, *Xcl = p3l;
    u16 *Ynh = p2h, *Ynl = p2l, *Xnh = p0h, *Xnl = p0l;
#pragma unroll 1
    for (int s5 = 0; s5 < 5; ++s5) {
        mmD(Ych, Ycl, Xch, Xcl, ti, tj, l, a1, a2);
        stP(Xnh, Xnl, ti, tj, l, a1);
        stP(Ynh, Ynl, tj, ti, l, a2);
        __syncthreads();
        u16* t;
        t = Xch; Xch = Xnh; Xnh = t;   t = Xcl; Xcl = Xnl; Xnl = t;
        t = Ych; Ych = Ynh; Ynh = t;   t = Ycl; Ycl = Ynl; Ynl = t;
    }

    // T = R^T: rm(T) = cm(R) = Yc, cm(T) = rm(R) = Xc. Store dense (stride 64).
    for (int s8 = tid; s8 < 512; s8 += 256) {
        const int base = s8 * 8, r = base >> 6, c = base & 63;
        u16* dst = wsP + g * 16384;
        *(uint4*)(dst + base)         = *(const uint4*)(Ych + r * LDW + c);  // rm hi
        *(uint4*)(dst + 4096 + base)  = *(const uint4*)(Ycl + r * LDW + c);  // rm lo
        *(uint4*)(dst + 8192 + base)  = *(const uint4*)(Xch + r * LDW + c);  // cm hi
        *(uint4*)(dst + 12288 + base) = *(const uint4*)(Xcl + r * LDW + c);  // cm lo
    }
}

// K2: chain tables E(p), p in [0,64). One block per p, 4 waves, 32x32 MFMA.
__global__ __launch_bounds__(256) void table_kernel(const u16* __restrict__ wsP,
                                                    u16* __restrict__ rm_bf,
                                                    u16* __restrict__ cm_bf)
{
    __shared__ u16 S[8 * PL];
    const int p = blockIdx.x, tid = threadIdx.x;
    const int w = tid >> 6, l = tid & 63;
    const int ti = w & 1, tj = w >> 1;

    if (p < 2) {
        for (int s = tid; s < 4096; s += 256) {
            u16 v = ((s >> 6) == (s & 63)) ? (u16)0x3F80 : (u16)0;
            rm_bf[p * 4096 + s] = v;
            cm_bf[p * 4096 + s] = v;
        }
        return;
    }
    const int d = 31 - __clz(p);

    if (d == 1) {  // table = T_b, rounded from hi+lo planes
        const u16* src = wsP + (p & 1) * 16384;
        for (int s = tid; s < 4096; s += 256) {
            rm_bf[p * 4096 + s] = f2bf(bf2f(src[s]) + bf2f(src[4096 + s]));
            cm_bf[p * 4096 + s] = f2bf(bf2f(src[8192 + s]) + bf2f(src[12288 + s]));
        }
        return;
    }

    u16* TAh = S;            u16* TAl = S + PL;       // cm(T0)
    u16* TBh = S + 2 * PL;   u16* TBl = S + 3 * PL;   // cm(T1)
    u16* Eah = S + 4 * PL;   u16* Eal = S + 5 * PL;   // E ping
    u16* Ebh = S + 6 * PL;   u16* Ebl = S + 7 * PL;   // E pong

    {
        const int b0 = p & 1;
        for (int s8 = tid; s8 < 512; s8 += 256) {
            const int base = s8 * 8, r = base >> 6, c = base & 63;
            *(uint4*)(TAh + r * LDW + c) = *(const uint4*)(wsP + 8192 + base);
            *(uint4*)(TAl + r * LDW + c) = *(const uint4*)(wsP + 12288 + base);
            *(uint4*)(TBh + r * LDW + c) = *(const uint4*)(wsP + 16384 + 8192 + base);
            *(uint4*)(TBl + r * LDW + c) = *(const uint4*)(wsP + 16384 + 12288 + base);
            *(uint4*)(Eah + r * LDW + c) = *(const uint4*)(wsP + b0 * 16384 + base);
            *(uint4*)(Eal + r * LDW + c) = *(const uint4*)(wsP + b0 * 16384 + 4096 + base);
        }
    }
    __syncthreads();

    fx16 acc, a1, a2;
    u16 *Ech = Eah, *Ecl = Eal, *Enh = Ebh, *Enl = Ebl;
#pragma unroll 1
    for (int j = 1; j <= d - 2; ++j) {
        const int b = (p >> j) & 1;
        mmS(b ? TBh : TAh, b ? TBl : TAl, Ech, Ecl, ti, tj, l, acc);
        stP(Enh, Enl, ti, tj, l, acc);
        __syncthreads();
        u16* t;
        t = Ech; Ech = Enh; Enh = t;   t = Ecl; Ecl = Enl; Enl = t;
    }
    {
        const int b = (p >> (d - 1)) & 1;
        mmD(b ? TBh : TAh, b ? TBl : TAl, Ech, Ecl, ti, tj, l, a1, a2);
        stG(rm_bf + p * 4096, ti, tj, l, a1);   // rm(E·T)
        stG(cm_bf + p * 4096, tj, ti, l, a2);   // cm(E·T)
    }
}

// K3: one wave per token. Content row + maps (copy or maps^T = E_hi^T · E_lo^T via MFMA).
__global__ __launch_bounds__(256) void out_kernel(const int* __restrict__ tt,
                                                  const int* __restrict__ tv,
                                                  const int* __restrict__ npos,
                                                  const float* __restrict__ embed,
                                                  const u16* __restrict__ rm_bf,
                                                  const u16* __restrict__ cm_bf,
                                                  float* __restrict__ out)
{
    const int tid = threadIdx.x;
    const int wv = tid >> 6, l = tid & 63;
    const int flat = blockIdx.x * 4 + wv;
    const int pos = npos[flat];

    {
        const int t = tt[flat], v = tv[flat];
        int idx; bool valid = true;
        if (t == 0)      idx = 0;
        else if (t == 1) idx = v + 1;
        else if (t == 2) idx = v + 5;
        else if (t == 4) idx = 8;
        else if (t == 3 && v == -1) idx = 10;
        else { idx = 0; valid = false; }
        out[flat * 64 + l] = valid ? embed[idx * 64 + l] : 0.f;
    }

    float* om = out + 4096 * 64 + (size_t)flat * 4096;

    if (pos < 64) {
        const u16* src = rm_bf + pos * 4096;
        for (int e = l * 8; e < 4096; e += 512) {
            uint4 ld = *(const uint4*)(src + e);
            fx4 lo, hi;
            lo[0] = __uint_as_float(ld.x << 16); lo[1] = __uint_as_float(ld.x & 0xFFFF0000u);
            lo[2] = __uint_as_float(ld.y << 16); lo[3] = __uint_as_float(ld.y & 0xFFFF0000u);
            hi[0] = __uint_as_float(ld.z << 16); hi[1] = __uint_as_float(ld.z & 0xFFFF0000u);
            hi[2] = __uint_as_float(ld.w << 16); hi[3] = __uint_as_float(ld.w & 0xFFFF0000u);
            __builtin_nontemporal_store(lo, (fx4*)(om + e));
            __builtin_nontemporal_store(hi, (fx4*)(om + e + 4));
        }
    } else {
        const int lo5 = (pos & 31) | 32;
        const int hi5 = pos >> 5;
        const u16* Acm = cm_bf + hi5 * 4096;   // A = E_hi^T
        const u16* Brm = rm_bf + lo5 * 4096;   // B = E_lo^T
        const int lr = l & 15, k8 = (l >> 4) * 8;

        bx8 A0[4], A1[4], B0[4], B1[4];
#pragma unroll
        for (int q = 0; q < 4; ++q) {
            A0[q] = *(const bx8*)(Acm + (q * 16 + lr) * 64 + k8);
            A1[q] = *(const bx8*)(Acm + (q * 16 + lr) * 64 + 32 + k8);
        }
#pragma unroll
        for (int c = 0; c < 4; ++c) {
            B0[c] = *(const bx8*)(Brm + (c * 16 + lr) * 64 + k8);
            B1[c] = *(const bx8*)(Brm + (c * 16 + lr) * 64 + 32 + k8);
        }
#pragma unroll
        for (int ct = 0; ct < 4; ++ct) {
#pragma unroll
            for (int q = 0; q < 4; ++q) {
                fx4 c4 = { 0.f, 0.f, 0.f, 0.f };
                c4 = __builtin_amdgcn_mfma_f32_16x16x32_bf16(A0[q], B0[ct], c4, 0, 0, 0);
                c4 = __builtin_amdgcn_mfma_f32_16x16x32_bf16(A1[q], B1[ct], c4, 0, 0, 0);
                __builtin_nontemporal_store(c4,
                    (fx4*)(om + (ct * 16 + lr) * 64 + q * 16 + 4 * (l >> 4)));
            }
        }
    }
}

extern "C" void kernel_launch(void* const* d_in, const int* in_sizes, int n_in,
                              void* d_out, int out_size, void* d_ws, size_t ws_size,
                              hipStream_t stream)
{
    const int*   tt    = (const int*)d_in[0];
    const int*   tv    = (const int*)d_in[1];
    const int*   np    = (const int*)d_in[2];
    const float* embed = (const float*)d_in[3];
    const float* praw  = (const float*)d_in[4];
    float* out = (float*)d_out;

    u16* wsP   = (u16*)d_ws;
    u16* rm_bf = (u16*)((char*)d_ws + 65536);
    u16* cm_bf = (u16*)((char*)d_ws + 65536 + 524288);

    expm_kernel<<<dim3(2), dim3(256), 0, stream>>>(praw, wsP);
    table_kernel<<<dim3(64), dim3(256), 0, stream>>>(wsP, rm_bf, cm_bf);
    out_kernel<<<dim3(1024), dim3(256), 0, stream>>>(tt, tv, np, embed, rm_bf, cm_bf, out);
}